// Round 1
// baseline (308.390 us; speedup 1.0000x reference)
//
#include <hip/hip_runtime.h>

#define N_NODES 4096
#define BATCH 128

// ---------------------------------------------------------------------------
// conn_T[j][i] = conn[i][j]  (so prop gather reads contiguous rows of conn_T)
// ---------------------------------------------------------------------------
__global__ __launch_bounds__(256) void transpose_kernel(const float* __restrict__ in,
                                                        float* __restrict__ out) {
  __shared__ float tile[32][33];
  const int bx = blockIdx.x, by = blockIdx.y;
  const int tx = threadIdx.x & 31;
  const int ty = threadIdx.x >> 5;  // 0..7
#pragma unroll
  for (int j = 0; j < 4; ++j) {
    const int r = ty + j * 8;
    tile[r][tx] = in[(size_t)(by * 32 + r) * N_NODES + bx * 32 + tx];
  }
  __syncthreads();
#pragma unroll
  for (int j = 0; j < 4; ++j) {
    const int r = ty + j * 8;
    out[(size_t)(bx * 32 + r) * N_NODES + by * 32 + tx] = tile[tx][r];
  }
}

// ---------------------------------------------------------------------------
// projected[b][i] = sum_k input[b][k] * W[i][k] + bias[i]
// f32 VALU GEMM, BM=64 BN=32 BK=16, 256 threads, 4x2 micro-tile per thread.
// ---------------------------------------------------------------------------
__global__ __launch_bounds__(256) void proj_gemm_kernel(const float* __restrict__ A,
                                                        const float* __restrict__ W,
                                                        const float* __restrict__ bias,
                                                        float* __restrict__ C) {
  const int K = N_NODES;
  __shared__ float As[16][65];  // [k][m]
  __shared__ float Bs[16][33];  // [k][n]
  const int tid = threadIdx.x;
  const int tx = tid & 15;      // n
  const int ty = tid >> 4;      // m
  const int m0 = blockIdx.y * 64, n0 = blockIdx.x * 32;
  const int arow = tid >> 2;        // 0..63
  const int ak = (tid & 3) * 4;     // k sub-offset
  float acc[4][2] = {};
  for (int k0 = 0; k0 < K; k0 += 16) {
    const float4 av = *(const float4*)(A + (size_t)(m0 + arow) * K + k0 + ak);
    float4 wv = make_float4(0.f, 0.f, 0.f, 0.f);
    if (tid < 128) wv = *(const float4*)(W + (size_t)(n0 + (tid >> 2)) * K + k0 + ak);
    __syncthreads();  // protect previous iteration's LDS reads
    As[ak + 0][arow] = av.x; As[ak + 1][arow] = av.y;
    As[ak + 2][arow] = av.z; As[ak + 3][arow] = av.w;
    if (tid < 128) {
      const int wr = tid >> 2;
      Bs[ak + 0][wr] = wv.x; Bs[ak + 1][wr] = wv.y;
      Bs[ak + 2][wr] = wv.z; Bs[ak + 3][wr] = wv.w;
    }
    __syncthreads();
#pragma unroll
    for (int kk = 0; kk < 16; ++kk) {
      const float a0 = As[kk][ty], a1 = As[kk][ty + 16];
      const float a2 = As[kk][ty + 32], a3 = As[kk][ty + 48];
      const float b0 = Bs[kk][tx], b1 = Bs[kk][tx + 16];
      acc[0][0] += a0 * b0; acc[0][1] += a0 * b1;
      acc[1][0] += a1 * b0; acc[1][1] += a1 * b1;
      acc[2][0] += a2 * b0; acc[2][1] += a2 * b1;
      acc[3][0] += a3 * b0; acc[3][1] += a3 * b1;
    }
  }
#pragma unroll
  for (int im = 0; im < 4; ++im) {
#pragma unroll
    for (int jn = 0; jn < 2; ++jn) {
      const int col = n0 + tx + 16 * jn;
      C[(size_t)(m0 + ty + 16 * im) * N_NODES + col] = acc[im][jn] + bias[col];
    }
  }
}

// ---------------------------------------------------------------------------
// One workgroup per sample. State in registers (1024 thr x float4 = 4096).
// Active set as a 4096-bit LDS mask; gather = deterministic ascending-j sum of
// conn_T rows (TRANSPOSED=1) or strided conn columns (TRANSPOSED=0 fallback).
// ---------------------------------------------------------------------------
template <int TRANSPOSED>
__global__ __launch_bounds__(1024) void avalanche_kernel(const float* __restrict__ proj,
                                                         const float* __restrict__ conn,
                                                         float* __restrict__ out,
                                                         unsigned int* __restrict__ maxslot) {
  const int b = blockIdx.x;
  const int t = threadIdx.x;
  __shared__ unsigned long long mask[64];
  __shared__ int cnt;

  float4 s = *(const float4*)(proj + (size_t)b * N_NODES + t * 4);
  float total = 0.0f;

  for (int it = 0; it < 100; ++it) {
    __syncthreads();  // protect mask/cnt from previous iteration's readers
    if (t < 64) mask[t] = 0ULL;
    if (t == 0) cnt = 0;
    __syncthreads();

    // detect actives among this thread's 4 nodes (node = 4*t + c)
    const float v0 = s.x, v1 = s.y, v2 = s.z, v3 = s.w;
    unsigned int bits = 0;
    int lc = 0;
    if (v0 > 1.0f) { bits |= 1u; ++lc; }
    if (v1 > 1.0f) { bits |= 2u; ++lc; }
    if (v2 > 1.0f) { bits |= 4u; ++lc; }
    if (v3 > 1.0f) { bits |= 8u; ++lc; }
    if (bits) atomicOr(&mask[t >> 4], (unsigned long long)bits << ((t & 15) * 4));
    if (lc) atomicAdd(&cnt, lc);
    __syncthreads();

    const int n = cnt;
    if (n == 0) break;  // sticky done: state frozen, stop accumulating
    total += (float)n;

    // prop[i] = sum over active j of conn[i][j]  (active is binary -> pure adds)
    float4 acc = make_float4(0.f, 0.f, 0.f, 0.f);
    for (int w = 0; w < 64; ++w) {
      unsigned long long m = mask[w];
      while (m) {
        const int j = (w << 6) + __builtin_ctzll(m);
        m &= m - 1;
        if (TRANSPOSED) {
          const float4 cv = *(const float4*)(conn + (size_t)j * N_NODES + t * 4);
          acc.x += cv.x; acc.y += cv.y; acc.z += cv.z; acc.w += cv.w;
        } else {
          acc.x += conn[(size_t)(t * 4 + 0) * N_NODES + j];
          acc.y += conn[(size_t)(t * 4 + 1) * N_NODES + j];
          acc.z += conn[(size_t)(t * 4 + 2) * N_NODES + j];
          acc.w += conn[(size_t)(t * 4 + 3) * N_NODES + j];
        }
      }
    }

    // new_state = (1-a)*(0.9*s + prop); uses OLD state's active flags
    s.x = (v0 > 1.0f) ? 0.0f : 0.9f * v0 + acc.x;
    s.y = (v1 > 1.0f) ? 0.0f : 0.9f * v1 + acc.y;
    s.z = (v2 > 1.0f) ? 0.0f : 0.9f * v2 + acc.z;
    s.w = (v3 > 1.0f) ? 0.0f : 0.9f * v3 + acc.w;
  }

  *(float4*)(out + (size_t)b * N_NODES + t * 4) = s;
  if (t == 0) atomicMax(maxslot, __float_as_uint(total));  // totals >= 0
}

// ---------------------------------------------------------------------------
extern "C" void kernel_launch(void* const* d_in, const int* in_sizes, int n_in,
                              void* d_out, int out_size, void* d_ws, size_t ws_size,
                              hipStream_t stream) {
  const float* input = (const float*)d_in[0];   // [128,4096]
  const float* W     = (const float*)d_in[1];   // [4096,4096]
  const float* bias  = (const float*)d_in[2];   // [4096]
  const float* conn  = (const float*)d_in[3];   // [4096,4096]
  float* out = (float*)d_out;                   // [128*4096] state + [1] max_size

  const size_t connT_bytes = (size_t)N_NODES * N_NODES * sizeof(float);
  const size_t proj_bytes  = (size_t)BATCH * N_NODES * sizeof(float);
  unsigned int* maxslot = (unsigned int*)(out + (size_t)BATCH * N_NODES);

  hipMemsetAsync(maxslot, 0, sizeof(unsigned int), stream);

  if (ws_size >= connT_bytes + proj_bytes) {
    float* connT = (float*)d_ws;
    float* proj  = (float*)((char*)d_ws + connT_bytes);
    transpose_kernel<<<dim3(128, 128), 256, 0, stream>>>(conn, connT);
    proj_gemm_kernel<<<dim3(128, 2), 256, 0, stream>>>(input, W, bias, proj);
    avalanche_kernel<1><<<BATCH, 1024, 0, stream>>>(proj, connT, out, maxslot);
  } else {
    float* proj = (ws_size >= proj_bytes) ? (float*)d_ws : out;  // in-place fallback
    proj_gemm_kernel<<<dim3(128, 2), 256, 0, stream>>>(input, W, bias, proj);
    avalanche_kernel<0><<<BATCH, 1024, 0, stream>>>(proj, conn, out, maxslot);
  }
}

// Round 2
// 160.355 us; speedup vs baseline: 1.9232x; 1.9232x over previous
//
#include <hip/hip_runtime.h>

#define N_NODES 4096
#define BATCH 128
#define SPLITK 8
#define BM 128
#define BN 64
#define BK 16

// ---------------------------------------------------------------------------
// connT_bf16[j][i] = bf16(conn[i][j])  — gather reads contiguous bf16 rows
// ---------------------------------------------------------------------------
__global__ __launch_bounds__(256) void transpose_bf16_kernel(const float* __restrict__ in,
                                                             unsigned short* __restrict__ out) {
  __shared__ float tile[32][33];
  const int bx = blockIdx.x, by = blockIdx.y;
  const int tx = threadIdx.x & 31;
  const int ty = threadIdx.x >> 5;  // 0..7
#pragma unroll
  for (int j = 0; j < 4; ++j) {
    const int r = ty + j * 8;
    tile[r][tx] = in[(size_t)(by * 32 + r) * N_NODES + bx * 32 + tx];
  }
  __syncthreads();
#pragma unroll
  for (int j = 0; j < 4; ++j) {
    const int r = ty + j * 8;
    const unsigned int u = __float_as_uint(tile[tx][r]);
    out[(size_t)(bx * 32 + r) * N_NODES + by * 32 + tx] =
        (unsigned short)((u + 0x7FFFu + ((u >> 16) & 1u)) >> 16);  // RNE
  }
}

// ---------------------------------------------------------------------------
// Split-K f32 GEMM: P[s][m][n] = sum_{k in chunk s} A[m][k]*W[n][k]
// BM=128 (all of M), BN=64, BK=16, 256 threads, 8x4 outputs/thread.
// Grid (N/BN, NSPLIT) = (64, NSPLIT). W fetched exactly once from HBM.
// ---------------------------------------------------------------------------
template <int NSPLIT>
__global__ __launch_bounds__(256) void proj_gemm_splitk(const float* __restrict__ A,
                                                        const float* __restrict__ W,
                                                        float* __restrict__ P) {
  constexpr int KC = N_NODES / NSPLIT;
  __shared__ float As[BK][BM + 4];  // [k][m], row stride 132 floats (16B-aligned)
  __shared__ float Bs[BK][BN + 4];  // [k][n], row stride 68 floats (16B-aligned)
  const int tid = threadIdx.x;
  const int n0 = blockIdx.x * BN;
  const int kb = blockIdx.y * KC;
  const int tx = tid & 15;       // n-group: cols n0 + tx*4 .. +3
  const int ty = tid >> 4;       // m-group: rows ty*4..+3 and 64+ty*4..+3
  const int arow = tid >> 1;     // 0..127
  const int acol = (tid & 1) * 8;
  const int brow = tid >> 2;     // 0..63
  const int bcol = (tid & 3) * 4;

  float acc[2][4][4] = {};
  const float* Aptr = A + (size_t)arow * N_NODES + kb + acol;
  const float* Wptr = W + (size_t)(n0 + brow) * N_NODES + kb + bcol;

  for (int k0 = 0; k0 < KC; k0 += BK) {
    const float4 a0 = *(const float4*)(Aptr + k0);
    const float4 a1 = *(const float4*)(Aptr + k0 + 4);
    const float4 bv = *(const float4*)(Wptr + k0);
    __syncthreads();  // protect previous iteration's LDS reads
    As[acol + 0][arow] = a0.x; As[acol + 1][arow] = a0.y;
    As[acol + 2][arow] = a0.z; As[acol + 3][arow] = a0.w;
    As[acol + 4][arow] = a1.x; As[acol + 5][arow] = a1.y;
    As[acol + 6][arow] = a1.z; As[acol + 7][arow] = a1.w;
    Bs[bcol + 0][brow] = bv.x; Bs[bcol + 1][brow] = bv.y;
    Bs[bcol + 2][brow] = bv.z; Bs[bcol + 3][brow] = bv.w;
    __syncthreads();
#pragma unroll
    for (int kk = 0; kk < BK; ++kk) {
      const float4 av0 = *(const float4*)&As[kk][ty * 4];
      const float4 av1 = *(const float4*)&As[kk][64 + ty * 4];
      const float4 bv4 = *(const float4*)&Bs[kk][tx * 4];
      const float am[8] = {av0.x, av0.y, av0.z, av0.w, av1.x, av1.y, av1.z, av1.w};
      const float bn[4] = {bv4.x, bv4.y, bv4.z, bv4.w};
#pragma unroll
      for (int i2 = 0; i2 < 2; ++i2)
#pragma unroll
        for (int i = 0; i < 4; ++i)
#pragma unroll
          for (int j = 0; j < 4; ++j)
            acc[i2][i][j] += am[i2 * 4 + i] * bn[j];
    }
  }

  float* outp = P + (size_t)blockIdx.y * BATCH * N_NODES + n0 + tx * 4;
#pragma unroll
  for (int i2 = 0; i2 < 2; ++i2)
#pragma unroll
    for (int i = 0; i < 4; ++i) {
      const int m = i2 * 64 + ty * 4 + i;
      *(float4*)(outp + (size_t)m * N_NODES) =
          make_float4(acc[i2][i][0], acc[i2][i][1], acc[i2][i][2], acc[i2][i][3]);
    }
}

// ---------------------------------------------------------------------------
// proj[m][n] = sum_s P[s][m][n] + bias[n]   (fixed order -> deterministic)
// Works in-place when proj == P and NSPLIT == 1.
// ---------------------------------------------------------------------------
template <int NSPLIT>
__global__ __launch_bounds__(256) void reduce_bias_kernel(const float* __restrict__ P,
                                                          const float* __restrict__ bias,
                                                          float* __restrict__ proj) {
  const size_t base = ((size_t)blockIdx.x * 256 + threadIdx.x) * 4;
  const int n = (int)(base & (N_NODES - 1));
  float4 s = *(const float4*)(P + base);
#pragma unroll
  for (int sp = 1; sp < NSPLIT; ++sp) {
    const float4 v = *(const float4*)(P + (size_t)sp * BATCH * N_NODES + base);
    s.x += v.x; s.y += v.y; s.z += v.z; s.w += v.w;
  }
  const float4 bv = *(const float4*)(bias + n);
  s.x += bv.x; s.y += bv.y; s.z += bv.z; s.w += bv.w;
  *(float4*)(proj + base) = s;
}

// ---------------------------------------------------------------------------
// One workgroup per sample; state in registers (1024 thr x float4).
// MODE 1: bf16 connT rows (coalesced).  MODE 0: f32 conn columns (fallback).
// ---------------------------------------------------------------------------
template <int MODE>
__global__ __launch_bounds__(1024) void avalanche_kernel(const float* __restrict__ proj,
                                                         const void* __restrict__ connv,
                                                         float* __restrict__ out,
                                                         unsigned int* __restrict__ maxslot) {
  const int b = blockIdx.x;
  const int t = threadIdx.x;
  __shared__ unsigned long long mask[64];
  __shared__ int cnt;

  float4 s = *(const float4*)(proj + (size_t)b * N_NODES + t * 4);
  float total = 0.0f;

  for (int it = 0; it < 100; ++it) {
    __syncthreads();
    if (t < 64) mask[t] = 0ULL;
    if (t == 0) cnt = 0;
    __syncthreads();

    const float v0 = s.x, v1 = s.y, v2 = s.z, v3 = s.w;
    unsigned int bits = 0;
    int lc = 0;
    if (v0 > 1.0f) { bits |= 1u; ++lc; }
    if (v1 > 1.0f) { bits |= 2u; ++lc; }
    if (v2 > 1.0f) { bits |= 4u; ++lc; }
    if (v3 > 1.0f) { bits |= 8u; ++lc; }
    if (bits) atomicOr(&mask[t >> 4], (unsigned long long)bits << ((t & 15) * 4));
    if (lc) atomicAdd(&cnt, lc);
    __syncthreads();

    const int n = cnt;
    if (n == 0) break;
    total += (float)n;

    float4 acc = make_float4(0.f, 0.f, 0.f, 0.f);
    for (int w = 0; w < 64; ++w) {
      unsigned long long m = mask[w];
      while (m) {
        const int j = (w << 6) + __builtin_ctzll(m);
        m &= m - 1;
        if (MODE == 1) {
          const ushort4 cv =
              *(const ushort4*)((const unsigned short*)connv + (size_t)j * N_NODES + t * 4);
          acc.x += __uint_as_float((unsigned int)cv.x << 16);
          acc.y += __uint_as_float((unsigned int)cv.y << 16);
          acc.z += __uint_as_float((unsigned int)cv.z << 16);
          acc.w += __uint_as_float((unsigned int)cv.w << 16);
        } else {
          const float* conn = (const float*)connv;
          acc.x += conn[(size_t)(t * 4 + 0) * N_NODES + j];
          acc.y += conn[(size_t)(t * 4 + 1) * N_NODES + j];
          acc.z += conn[(size_t)(t * 4 + 2) * N_NODES + j];
          acc.w += conn[(size_t)(t * 4 + 3) * N_NODES + j];
        }
      }
    }

    s.x = (v0 > 1.0f) ? 0.0f : 0.9f * v0 + acc.x;
    s.y = (v1 > 1.0f) ? 0.0f : 0.9f * v1 + acc.y;
    s.z = (v2 > 1.0f) ? 0.0f : 0.9f * v2 + acc.z;
    s.w = (v3 > 1.0f) ? 0.0f : 0.9f * v3 + acc.w;
  }

  *(float4*)(out + (size_t)b * N_NODES + t * 4) = s;
  if (t == 0) atomicMax(maxslot, __float_as_uint(total));  // totals >= 0
}

// ---------------------------------------------------------------------------
extern "C" void kernel_launch(void* const* d_in, const int* in_sizes, int n_in,
                              void* d_out, int out_size, void* d_ws, size_t ws_size,
                              hipStream_t stream) {
  const float* input = (const float*)d_in[0];  // [128,4096]
  const float* W     = (const float*)d_in[1];  // [4096,4096] (row i = output i)
  const float* bias  = (const float*)d_in[2];  // [4096]
  const float* conn  = (const float*)d_in[3];  // [4096,4096]
  float* out = (float*)d_out;                  // [128*4096] state + [1] max_size

  const size_t connT_bytes = (size_t)N_NODES * N_NODES * sizeof(unsigned short);  // 32 MB
  const size_t part_bytes  = (size_t)SPLITK * BATCH * N_NODES * sizeof(float);    // 16 MB
  const size_t proj_bytes  = (size_t)BATCH * N_NODES * sizeof(float);             //  2 MB
  unsigned int* maxslot = (unsigned int*)(out + (size_t)BATCH * N_NODES);

  hipMemsetAsync(maxslot, 0, sizeof(unsigned int), stream);

  if (ws_size >= connT_bytes + part_bytes + proj_bytes) {
    unsigned short* connT = (unsigned short*)d_ws;
    float* part = (float*)((char*)d_ws + connT_bytes);
    float* proj = (float*)((char*)d_ws + connT_bytes + part_bytes);
    transpose_bf16_kernel<<<dim3(128, 128), 256, 0, stream>>>(conn, connT);
    proj_gemm_splitk<SPLITK><<<dim3(N_NODES / BN, SPLITK), 256, 0, stream>>>(input, W, part);
    reduce_bias_kernel<SPLITK><<<BATCH * N_NODES / 1024, 256, 0, stream>>>(part, bias, proj);
    avalanche_kernel<1><<<BATCH, 1024, 0, stream>>>(proj, connT, out, maxslot);
  } else {
    // Fallback: no workspace — GEMM into d_out, in-place bias, strided gather.
    proj_gemm_splitk<1><<<dim3(N_NODES / BN, 1), 256, 0, stream>>>(input, W, out);
    reduce_bias_kernel<1><<<BATCH * N_NODES / 1024, 256, 0, stream>>>(out, bias, out);
    avalanche_kernel<0><<<BATCH, 1024, 0, stream>>>(out, conn, out, maxslot);
  }
}

// Round 3
// 120.183 us; speedup vs baseline: 2.5660x; 1.3343x over previous
//
#include <hip/hip_runtime.h>

#define N_NODES 4096
#define BATCH 128
#define SPLITK 16
#define BM 128
#define BN 64
#define BK 16

// ---------------------------------------------------------------------------
// connT_bf16[j][i] = bf16(conn[i][j])  — gather reads contiguous bf16 rows
// ---------------------------------------------------------------------------
__global__ __launch_bounds__(256) void transpose_bf16_kernel(const float* __restrict__ in,
                                                             unsigned short* __restrict__ out) {
  __shared__ float tile[32][33];
  const int bx = blockIdx.x, by = blockIdx.y;
  const int tx = threadIdx.x & 31;
  const int ty = threadIdx.x >> 5;  // 0..7
#pragma unroll
  for (int j = 0; j < 4; ++j) {
    const int r = ty + j * 8;
    tile[r][tx] = in[(size_t)(by * 32 + r) * N_NODES + bx * 32 + tx];
  }
  __syncthreads();
#pragma unroll
  for (int j = 0; j < 4; ++j) {
    const int r = ty + j * 8;
    const unsigned int u = __float_as_uint(tile[tx][r]);
    out[(size_t)(bx * 32 + r) * N_NODES + by * 32 + tx] =
        (unsigned short)((u + 0x7FFFu + ((u >> 16) & 1u)) >> 16);  // RNE
  }
}

// ---------------------------------------------------------------------------
// Split-K f32 GEMM: P[s][m][n] = sum_{k in chunk s} A[m][k]*W[n][k]
// BM=128 (all of M), BN=64, BK=16, 256 threads, 8x4 outputs/thread.
// Grid (N/BN, NSPLIT). NSPLIT=16 -> 1024 blocks -> 4 blocks/CU.
// ---------------------------------------------------------------------------
template <int NSPLIT>
__global__ __launch_bounds__(256) void proj_gemm_splitk(const float* __restrict__ A,
                                                        const float* __restrict__ W,
                                                        float* __restrict__ P) {
  constexpr int KC = N_NODES / NSPLIT;
  __shared__ float As[BK][BM + 4];  // [k][m]
  __shared__ float Bs[BK][BN + 4];  // [k][n]
  const int tid = threadIdx.x;
  const int n0 = blockIdx.x * BN;
  const int kb = blockIdx.y * KC;
  const int tx = tid & 15;       // n-group
  const int ty = tid >> 4;       // m-group
  const int arow = tid >> 1;     // 0..127
  const int acol = (tid & 1) * 8;
  const int brow = tid >> 2;     // 0..63
  const int bcol = (tid & 3) * 4;

  float acc[2][4][4] = {};
  const float* Aptr = A + (size_t)arow * N_NODES + kb + acol;
  const float* Wptr = W + (size_t)(n0 + brow) * N_NODES + kb + bcol;

  for (int k0 = 0; k0 < KC; k0 += BK) {
    const float4 a0 = *(const float4*)(Aptr + k0);
    const float4 a1 = *(const float4*)(Aptr + k0 + 4);
    const float4 bv = *(const float4*)(Wptr + k0);
    __syncthreads();  // protect previous iteration's LDS reads
    As[acol + 0][arow] = a0.x; As[acol + 1][arow] = a0.y;
    As[acol + 2][arow] = a0.z; As[acol + 3][arow] = a0.w;
    As[acol + 4][arow] = a1.x; As[acol + 5][arow] = a1.y;
    As[acol + 6][arow] = a1.z; As[acol + 7][arow] = a1.w;
    Bs[bcol + 0][brow] = bv.x; Bs[bcol + 1][brow] = bv.y;
    Bs[bcol + 2][brow] = bv.z; Bs[bcol + 3][brow] = bv.w;
    __syncthreads();
#pragma unroll
    for (int kk = 0; kk < BK; ++kk) {
      const float4 av0 = *(const float4*)&As[kk][ty * 4];
      const float4 av1 = *(const float4*)&As[kk][64 + ty * 4];
      const float4 bv4 = *(const float4*)&Bs[kk][tx * 4];
      const float am[8] = {av0.x, av0.y, av0.z, av0.w, av1.x, av1.y, av1.z, av1.w};
      const float bn[4] = {bv4.x, bv4.y, bv4.z, bv4.w};
#pragma unroll
      for (int i2 = 0; i2 < 2; ++i2)
#pragma unroll
        for (int i = 0; i < 4; ++i)
#pragma unroll
          for (int j = 0; j < 4; ++j)
            acc[i2][i][j] += am[i2 * 4 + i] * bn[j];
    }
  }

  float* outp = P + (size_t)blockIdx.y * BATCH * N_NODES + n0 + tx * 4;
#pragma unroll
  for (int i2 = 0; i2 < 2; ++i2)
#pragma unroll
    for (int i = 0; i < 4; ++i) {
      const int m = i2 * 64 + ty * 4 + i;
      *(float4*)(outp + (size_t)m * N_NODES) =
          make_float4(acc[i2][i][0], acc[i2][i][1], acc[i2][i][2], acc[i2][i][3]);
    }
}

// ---------------------------------------------------------------------------
// Fallback-only: proj[m][n] = P[m][n] + bias[n] in place.
// ---------------------------------------------------------------------------
__global__ __launch_bounds__(256) void bias_inplace_kernel(float* __restrict__ P,
                                                           const float* __restrict__ bias) {
  const size_t base = ((size_t)blockIdx.x * 256 + threadIdx.x) * 4;
  const int n = (int)(base & (N_NODES - 1));
  float4 s = *(const float4*)(P + base);
  const float4 bv = *(const float4*)(bias + n);
  s.x += bv.x; s.y += bv.y; s.z += bv.z; s.w += bv.w;
  *(float4*)(P + base) = s;
}

// ---------------------------------------------------------------------------
// One workgroup per sample; state in registers (1024 thr x float4).
// MODE 1: prologue reduces NSPLIT GEMM partials + bias; gather reads bf16
//         connT rows via an ordered LDS active-list with 4-way unroll.
// MODE 0: proj precomputed (bias applied); f32 conn column gather (fallback).
// ---------------------------------------------------------------------------
template <int MODE, int NSPLIT>
__global__ __launch_bounds__(1024) void avalanche_kernel(const float* __restrict__ Pin,
                                                         const float* __restrict__ bias,
                                                         const void* __restrict__ connv,
                                                         float* __restrict__ out,
                                                         unsigned int* __restrict__ maxslot) {
  const int b = blockIdx.x;
  const int t = threadIdx.x;
  __shared__ unsigned long long mask[64];
  __shared__ int wincl[64];   // inclusive prefix of per-word popcounts
  __shared__ int list[N_NODES];

  // --- state init: reduce split-K partials + bias (MODE 1) or plain load ---
  float4 s;
  if (MODE == 1) {
    const float4 bv = *(const float4*)(bias + t * 4);
    s = bv;
#pragma unroll
    for (int sp = 0; sp < NSPLIT; ++sp) {
      const float4 v = *(const float4*)(Pin + (size_t)sp * BATCH * N_NODES +
                                        (size_t)b * N_NODES + t * 4);
      s.x += v.x; s.y += v.y; s.z += v.z; s.w += v.w;
    }
  } else {
    s = *(const float4*)(Pin + (size_t)b * N_NODES + t * 4);
  }

  float total = 0.0f;

  for (int it = 0; it < 100; ++it) {
    const float v0 = s.x, v1 = s.y, v2 = s.z, v3 = s.w;
    unsigned int bits = 0;
    if (v0 > 1.0f) bits |= 1u;
    if (v1 > 1.0f) bits |= 2u;
    if (v2 > 1.0f) bits |= 4u;
    if (v3 > 1.0f) bits |= 8u;

    __syncthreads();  // previous iteration's list/mask readers are done
    if (t < 64) mask[t] = 0ULL;
    __syncthreads();
    if (bits) atomicOr(&mask[t >> 4], (unsigned long long)bits << ((t & 15) * 4));
    __syncthreads();

    // ordered active-list build: per-word popcount + wave-scan prefix
    if (t < 64) {
      int incl = __popcll(mask[t]);
#pragma unroll
      for (int d = 1; d < 64; d <<= 1) {
        const int y = __shfl_up(incl, d);
        if (t >= d) incl += y;
      }
      wincl[t] = incl;
    }
    __syncthreads();
    const int n = wincl[63];
    if (n == 0) break;  // sticky done: state frozen
    total += (float)n;

    if (t < 64) {
      unsigned long long m = mask[t];
      int o = wincl[t] - __popcll(m);
      while (m) {
        list[o++] = (t << 6) + __builtin_ctzll(m);
        m &= m - 1;
      }
    }
    __syncthreads();

    // gather: prop[i] = sum over active j (ascending) of conn[i][j]
    float4 a0 = make_float4(0.f, 0.f, 0.f, 0.f), a1 = a0, a2 = a0, a3 = a0;
    if (MODE == 1) {
      const unsigned short* cT = (const unsigned short*)connv;
      int idx = 0;
      for (; idx + 4 <= n; idx += 4) {
        const int j0 = list[idx], j1 = list[idx + 1], j2 = list[idx + 2], j3 = list[idx + 3];
        const ushort4 c0 = *(const ushort4*)(cT + ((size_t)j0 << 12) + t * 4);
        const ushort4 c1 = *(const ushort4*)(cT + ((size_t)j1 << 12) + t * 4);
        const ushort4 c2 = *(const ushort4*)(cT + ((size_t)j2 << 12) + t * 4);
        const ushort4 c3 = *(const ushort4*)(cT + ((size_t)j3 << 12) + t * 4);
        a0.x += __uint_as_float((unsigned int)c0.x << 16);
        a0.y += __uint_as_float((unsigned int)c0.y << 16);
        a0.z += __uint_as_float((unsigned int)c0.z << 16);
        a0.w += __uint_as_float((unsigned int)c0.w << 16);
        a1.x += __uint_as_float((unsigned int)c1.x << 16);
        a1.y += __uint_as_float((unsigned int)c1.y << 16);
        a1.z += __uint_as_float((unsigned int)c1.z << 16);
        a1.w += __uint_as_float((unsigned int)c1.w << 16);
        a2.x += __uint_as_float((unsigned int)c2.x << 16);
        a2.y += __uint_as_float((unsigned int)c2.y << 16);
        a2.z += __uint_as_float((unsigned int)c2.z << 16);
        a2.w += __uint_as_float((unsigned int)c2.w << 16);
        a3.x += __uint_as_float((unsigned int)c3.x << 16);
        a3.y += __uint_as_float((unsigned int)c3.y << 16);
        a3.z += __uint_as_float((unsigned int)c3.z << 16);
        a3.w += __uint_as_float((unsigned int)c3.w << 16);
      }
      for (; idx < n; ++idx) {
        const int j = list[idx];
        const ushort4 c = *(const ushort4*)(cT + ((size_t)j << 12) + t * 4);
        a0.x += __uint_as_float((unsigned int)c.x << 16);
        a0.y += __uint_as_float((unsigned int)c.y << 16);
        a0.z += __uint_as_float((unsigned int)c.z << 16);
        a0.w += __uint_as_float((unsigned int)c.w << 16);
      }
    } else {
      const float* conn = (const float*)connv;
      for (int idx = 0; idx < n; ++idx) {
        const int j = list[idx];
        a0.x += conn[(size_t)(t * 4 + 0) * N_NODES + j];
        a0.y += conn[(size_t)(t * 4 + 1) * N_NODES + j];
        a0.z += conn[(size_t)(t * 4 + 2) * N_NODES + j];
        a0.w += conn[(size_t)(t * 4 + 3) * N_NODES + j];
      }
    }
    const float4 acc = make_float4((a0.x + a1.x) + (a2.x + a3.x),
                                   (a0.y + a1.y) + (a2.y + a3.y),
                                   (a0.z + a1.z) + (a2.z + a3.z),
                                   (a0.w + a1.w) + (a2.w + a3.w));

    // new_state = (1-a)*(0.9*s + prop); uses OLD state's active flags
    s.x = (v0 > 1.0f) ? 0.0f : 0.9f * v0 + acc.x;
    s.y = (v1 > 1.0f) ? 0.0f : 0.9f * v1 + acc.y;
    s.z = (v2 > 1.0f) ? 0.0f : 0.9f * v2 + acc.z;
    s.w = (v3 > 1.0f) ? 0.0f : 0.9f * v3 + acc.w;
  }

  *(float4*)(out + (size_t)b * N_NODES + t * 4) = s;
  if (t == 0) atomicMax(maxslot, __float_as_uint(total));  // totals >= 0
}

// ---------------------------------------------------------------------------
extern "C" void kernel_launch(void* const* d_in, const int* in_sizes, int n_in,
                              void* d_out, int out_size, void* d_ws, size_t ws_size,
                              hipStream_t stream) {
  const float* input = (const float*)d_in[0];  // [128,4096]
  const float* W     = (const float*)d_in[1];  // [4096,4096] (row i = output i)
  const float* bias  = (const float*)d_in[2];  // [4096]
  const float* conn  = (const float*)d_in[3];  // [4096,4096]
  float* out = (float*)d_out;                  // [128*4096] state + [1] max_size

  const size_t connT_bytes = (size_t)N_NODES * N_NODES * sizeof(unsigned short);  // 32 MB
  const size_t part_bytes  = (size_t)SPLITK * BATCH * N_NODES * sizeof(float);    // 32 MB
  unsigned int* maxslot = (unsigned int*)(out + (size_t)BATCH * N_NODES);

  hipMemsetAsync(maxslot, 0, sizeof(unsigned int), stream);

  if (ws_size >= connT_bytes + part_bytes) {
    unsigned short* connT = (unsigned short*)d_ws;
    float* part = (float*)((char*)d_ws + connT_bytes);
    transpose_bf16_kernel<<<dim3(128, 128), 256, 0, stream>>>(conn, connT);
    proj_gemm_splitk<SPLITK><<<dim3(N_NODES / BN, SPLITK), 256, 0, stream>>>(input, W, part);
    avalanche_kernel<1, SPLITK><<<BATCH, 1024, 0, stream>>>(part, bias, connT, out, maxslot);
  } else {
    // Fallback: no workspace — GEMM into d_out, in-place bias, strided gather.
    proj_gemm_splitk<1><<<dim3(N_NODES / BN, 1), 256, 0, stream>>>(input, W, out);
    bias_inplace_kernel<<<BATCH * N_NODES / 1024, 256, 0, stream>>>(out, bias);
    avalanche_kernel<0, 1><<<BATCH, 1024, 0, stream>>>(out, nullptr, conn, out, maxslot);
  }
}

// Round 4
// 87.639 us; speedup vs baseline: 3.5189x; 1.3713x over previous
//
#include <hip/hip_runtime.h>

#define N_NODES 4096
#define BATCH 128
#define SPLITK 16
#define GBN 64  // GEMM N-tile

typedef _Float16 f16x4 __attribute__((ext_vector_type(4)));
typedef _Float16 f16x8 __attribute__((ext_vector_type(8)));
typedef float f32x4 __attribute__((ext_vector_type(4)));

// ---------------------------------------------------------------------------
// connT_bf16[j][i] = bf16(conn[i][j])  — gather reads contiguous bf16 rows
// ---------------------------------------------------------------------------
__global__ __launch_bounds__(256) void transpose_bf16_kernel(const float* __restrict__ in,
                                                             unsigned short* __restrict__ out) {
  __shared__ float tile[32][33];
  const int bx = blockIdx.x, by = blockIdx.y;
  const int tx = threadIdx.x & 31;
  const int ty = threadIdx.x >> 5;  // 0..7
#pragma unroll
  for (int j = 0; j < 4; ++j) {
    const int r = ty + j * 8;
    tile[r][tx] = in[(size_t)(by * 32 + r) * N_NODES + bx * 32 + tx];
  }
  __syncthreads();
#pragma unroll
  for (int j = 0; j < 4; ++j) {
    const int r = ty + j * 8;
    const unsigned int u = __float_as_uint(tile[tx][r]);
    out[(size_t)(bx * 32 + r) * N_NODES + by * 32 + tx] =
        (unsigned short)((u + 0x7FFFu + ((u >> 16) & 1u)) >> 16);  // RNE
  }
}

// ---------------------------------------------------------------------------
// Split-f16 MFMA GEMM: P[s][m][n] = sum_{k in chunk s} A[m][k]*W[n][k] via
// Ah*Bh + Ah*Bl + Al*Bh (f32 accum). A pre-scaled x256, W x64; epilogue x2^-14.
// BM=128 (all M), BN=64, BK=32, 256 threads (4 waves, 2x2), 8x 16x16 C-frags
// per wave (4 in M x 2 in N). Grid (N/64, SPLITK) = (64,16) = 1024 blocks.
// ---------------------------------------------------------------------------
template <int NSPLIT>
__global__ __launch_bounds__(256) void proj_gemm_mfma(const float* __restrict__ A,
                                                      const float* __restrict__ W,
                                                      float* __restrict__ P) {
  constexpr int KC = N_NODES / NSPLIT;
  constexpr int PITCH = 40;  // f16 units per LDS row (32 + 8 pad)
  __shared__ alignas(16) _Float16 Ah[128 * PITCH], Al[128 * PITCH];
  __shared__ alignas(16) _Float16 Bh[GBN * PITCH], Bl[GBN * PITCH];

  const int tid = threadIdx.x;
  const int wave = tid >> 6, lane = tid & 63;
  const int wm = wave >> 1, wn = wave & 1;   // 2x2 wave grid
  const int g = lane >> 4, lrow = lane & 15; // frag lane coords
  const int n0 = blockIdx.x * GBN;
  const int kb = blockIdx.y * KC;
  const int scol = (tid & 7) * 4;            // staging k-offset (float4)
  const int srow = tid >> 3;                 // 0..31

  const float* Abase = A + (size_t)srow * N_NODES + kb + scol;
  const float* Wbase = W + (size_t)(n0 + srow) * N_NODES + kb + scol;

  f32x4 acc[4][2] = {};

  for (int k2 = 0; k2 < KC; k2 += 32) {
    float4 av[4], wv[2];
#pragma unroll
    for (int r = 0; r < 4; ++r)
      av[r] = *(const float4*)(Abase + (size_t)(r * 32) * N_NODES + k2);
#pragma unroll
    for (int r = 0; r < 2; ++r)
      wv[r] = *(const float4*)(Wbase + (size_t)(r * 32) * N_NODES + k2);

    __syncthreads();  // previous iteration's LDS readers done
#pragma unroll
    for (int r = 0; r < 4; ++r) {
      const int row = srow + r * 32;
      f16x4 hi, lo;
      const float x0 = av[r].x * 256.f, x1 = av[r].y * 256.f,
                  x2 = av[r].z * 256.f, x3 = av[r].w * 256.f;
      hi[0] = (_Float16)x0; lo[0] = (_Float16)(x0 - (float)hi[0]);
      hi[1] = (_Float16)x1; lo[1] = (_Float16)(x1 - (float)hi[1]);
      hi[2] = (_Float16)x2; lo[2] = (_Float16)(x2 - (float)hi[2]);
      hi[3] = (_Float16)x3; lo[3] = (_Float16)(x3 - (float)hi[3]);
      *(f16x4*)&Ah[row * PITCH + scol] = hi;
      *(f16x4*)&Al[row * PITCH + scol] = lo;
    }
#pragma unroll
    for (int r = 0; r < 2; ++r) {
      const int row = srow + r * 32;
      f16x4 hi, lo;
      const float x0 = wv[r].x * 64.f, x1 = wv[r].y * 64.f,
                  x2 = wv[r].z * 64.f, x3 = wv[r].w * 64.f;
      hi[0] = (_Float16)x0; lo[0] = (_Float16)(x0 - (float)hi[0]);
      hi[1] = (_Float16)x1; lo[1] = (_Float16)(x1 - (float)hi[1]);
      hi[2] = (_Float16)x2; lo[2] = (_Float16)(x2 - (float)hi[2]);
      hi[3] = (_Float16)x3; lo[3] = (_Float16)(x3 - (float)hi[3]);
      *(f16x4*)&Bh[row * PITCH + scol] = hi;
      *(f16x4*)&Bl[row * PITCH + scol] = lo;
    }
    __syncthreads();

    f16x8 ah[4], al[4], bh[2], bl[2];
#pragma unroll
    for (int fm = 0; fm < 4; ++fm) {
      const int m = wm * 64 + fm * 16 + lrow;
      ah[fm] = *(const f16x8*)&Ah[m * PITCH + g * 8];
      al[fm] = *(const f16x8*)&Al[m * PITCH + g * 8];
    }
#pragma unroll
    for (int fn = 0; fn < 2; ++fn) {
      const int n = wn * 32 + fn * 16 + lrow;
      bh[fn] = *(const f16x8*)&Bh[n * PITCH + g * 8];
      bl[fn] = *(const f16x8*)&Bl[n * PITCH + g * 8];
    }
#pragma unroll
    for (int fm = 0; fm < 4; ++fm)
#pragma unroll
      for (int fn = 0; fn < 2; ++fn) {
        acc[fm][fn] = __builtin_amdgcn_mfma_f32_16x16x32_f16(ah[fm], bh[fn], acc[fm][fn], 0, 0, 0);
        acc[fm][fn] = __builtin_amdgcn_mfma_f32_16x16x32_f16(ah[fm], bl[fn], acc[fm][fn], 0, 0, 0);
        acc[fm][fn] = __builtin_amdgcn_mfma_f32_16x16x32_f16(al[fm], bh[fn], acc[fm][fn], 0, 0, 0);
      }
  }

  // epilogue: D row = (lane>>4)*4 + reg, col = lane&15 (HW-verified layout)
  constexpr float INV = 1.0f / 16384.0f;  // 1/(256*64)
  float* Pbase = P + (size_t)blockIdx.y * BATCH * N_NODES;
#pragma unroll
  for (int fm = 0; fm < 4; ++fm)
#pragma unroll
    for (int fn = 0; fn < 2; ++fn) {
      const int n = n0 + wn * 32 + fn * 16 + lrow;
#pragma unroll
      for (int reg = 0; reg < 4; ++reg) {
        const int m = wm * 64 + fm * 16 + g * 4 + reg;
        Pbase[(size_t)m * N_NODES + n] = acc[fm][fn][reg] * INV;
      }
    }
}

// ---------------------------------------------------------------------------
// Fallback-only f32 VALU GEMM (no workspace): P[m][n] = sum_k A[m][k]*W[n][k]
// ---------------------------------------------------------------------------
__global__ __launch_bounds__(256) void proj_gemm_valu(const float* __restrict__ A,
                                                      const float* __restrict__ W,
                                                      float* __restrict__ P) {
  __shared__ float As[16][132];
  __shared__ float Bs[16][68];
  const int tid = threadIdx.x;
  const int n0 = blockIdx.x * 64;
  const int tx = tid & 15, ty = tid >> 4;
  const int arow = tid >> 1, acol = (tid & 1) * 8;
  const int brow = tid >> 2, bcol = (tid & 3) * 4;
  float acc[2][4][4] = {};
  const float* Aptr = A + (size_t)arow * N_NODES + acol;
  const float* Wptr = W + (size_t)(n0 + brow) * N_NODES + bcol;
  for (int k0 = 0; k0 < N_NODES; k0 += 16) {
    const float4 a0 = *(const float4*)(Aptr + k0);
    const float4 a1 = *(const float4*)(Aptr + k0 + 4);
    const float4 bv = *(const float4*)(Wptr + k0);
    __syncthreads();
    As[acol + 0][arow] = a0.x; As[acol + 1][arow] = a0.y;
    As[acol + 2][arow] = a0.z; As[acol + 3][arow] = a0.w;
    As[acol + 4][arow] = a1.x; As[acol + 5][arow] = a1.y;
    As[acol + 6][arow] = a1.z; As[acol + 7][arow] = a1.w;
    Bs[bcol + 0][brow] = bv.x; Bs[bcol + 1][brow] = bv.y;
    Bs[bcol + 2][brow] = bv.z; Bs[bcol + 3][brow] = bv.w;
    __syncthreads();
#pragma unroll
    for (int kk = 0; kk < 16; ++kk) {
      const float4 av0 = *(const float4*)&As[kk][ty * 4];
      const float4 av1 = *(const float4*)&As[kk][64 + ty * 4];
      const float4 bv4 = *(const float4*)&Bs[kk][tx * 4];
      const float am[8] = {av0.x, av0.y, av0.z, av0.w, av1.x, av1.y, av1.z, av1.w};
      const float bn[4] = {bv4.x, bv4.y, bv4.z, bv4.w};
#pragma unroll
      for (int i2 = 0; i2 < 2; ++i2)
#pragma unroll
        for (int i = 0; i < 4; ++i)
#pragma unroll
          for (int j = 0; j < 4; ++j)
            acc[i2][i][j] += am[i2 * 4 + i] * bn[j];
    }
  }
#pragma unroll
  for (int i2 = 0; i2 < 2; ++i2)
#pragma unroll
    for (int i = 0; i < 4; ++i) {
      const int m = i2 * 64 + ty * 4 + i;
      *(float4*)(P + (size_t)m * N_NODES + n0 + tx * 4) =
          make_float4(acc[i2][i][0], acc[i2][i][1], acc[i2][i][2], acc[i2][i][3]);
    }
}

__global__ __launch_bounds__(256) void bias_inplace_kernel(float* __restrict__ P,
                                                           const float* __restrict__ bias) {
  const size_t base = ((size_t)blockIdx.x * 256 + threadIdx.x) * 4;
  const int n = (int)(base & (N_NODES - 1));
  float4 s = *(const float4*)(P + base);
  const float4 bv = *(const float4*)(bias + n);
  s.x += bv.x; s.y += bv.y; s.z += bv.z; s.w += bv.w;
  *(float4*)(P + base) = s;
}

// ---------------------------------------------------------------------------
// One workgroup per sample; state in registers (1024 thr x float4).
// MODE 1: prologue reduces NSPLIT GEMM partials + bias; ordered active-list
//         gather over bf16 connT rows, 4-way unrolled.
// MODE 0: proj precomputed; f32 conn column gather (fallback).
// ---------------------------------------------------------------------------
template <int MODE, int NSPLIT>
__global__ __launch_bounds__(1024) void avalanche_kernel(const float* __restrict__ Pin,
                                                         const float* __restrict__ bias,
                                                         const void* __restrict__ connv,
                                                         float* __restrict__ out,
                                                         unsigned int* __restrict__ maxslot) {
  const int b = blockIdx.x;
  const int t = threadIdx.x;
  __shared__ unsigned long long mask[64];
  __shared__ int wincl[64];
  __shared__ int list[N_NODES];

  float4 s;
  if (MODE == 1) {
    const float4 bv = *(const float4*)(bias + t * 4);
    s = bv;
#pragma unroll
    for (int sp = 0; sp < NSPLIT; ++sp) {
      const float4 v = *(const float4*)(Pin + (size_t)sp * BATCH * N_NODES +
                                        (size_t)b * N_NODES + t * 4);
      s.x += v.x; s.y += v.y; s.z += v.z; s.w += v.w;
    }
  } else {
    s = *(const float4*)(Pin + (size_t)b * N_NODES + t * 4);
  }

  float total = 0.0f;

  for (int it = 0; it < 100; ++it) {
    const float v0 = s.x, v1 = s.y, v2 = s.z, v3 = s.w;
    unsigned int bits = 0;
    if (v0 > 1.0f) bits |= 1u;
    if (v1 > 1.0f) bits |= 2u;
    if (v2 > 1.0f) bits |= 4u;
    if (v3 > 1.0f) bits |= 8u;

    __syncthreads();
    if (t < 64) mask[t] = 0ULL;
    __syncthreads();
    if (bits) atomicOr(&mask[t >> 4], (unsigned long long)bits << ((t & 15) * 4));
    __syncthreads();

    if (t < 64) {
      int incl = __popcll(mask[t]);
#pragma unroll
      for (int d = 1; d < 64; d <<= 1) {
        const int y = __shfl_up(incl, d);
        if (t >= d) incl += y;
      }
      wincl[t] = incl;
    }
    __syncthreads();
    const int n = wincl[63];
    if (n == 0) break;  // sticky done: state frozen
    total += (float)n;

    if (t < 64) {
      unsigned long long m = mask[t];
      int o = wincl[t] - __popcll(m);
      while (m) {
        list[o++] = (t << 6) + __builtin_ctzll(m);
        m &= m - 1;
      }
    }
    __syncthreads();

    float4 a0 = make_float4(0.f, 0.f, 0.f, 0.f), a1 = a0, a2 = a0, a3 = a0;
    if (MODE == 1) {
      const unsigned short* cT = (const unsigned short*)connv;
      int idx = 0;
      for (; idx + 4 <= n; idx += 4) {
        const int j0 = list[idx], j1 = list[idx + 1], j2 = list[idx + 2], j3 = list[idx + 3];
        const ushort4 c0 = *(const ushort4*)(cT + ((size_t)j0 << 12) + t * 4);
        const ushort4 c1 = *(const ushort4*)(cT + ((size_t)j1 << 12) + t * 4);
        const ushort4 c2 = *(const ushort4*)(cT + ((size_t)j2 << 12) + t * 4);
        const ushort4 c3 = *(const ushort4*)(cT + ((size_t)j3 << 12) + t * 4);
        a0.x += __uint_as_float((unsigned int)c0.x << 16);
        a0.y += __uint_as_float((unsigned int)c0.y << 16);
        a0.z += __uint_as_float((unsigned int)c0.z << 16);
        a0.w += __uint_as_float((unsigned int)c0.w << 16);
        a1.x += __uint_as_float((unsigned int)c1.x << 16);
        a1.y += __uint_as_float((unsigned int)c1.y << 16);
        a1.z += __uint_as_float((unsigned int)c1.z << 16);
        a1.w += __uint_as_float((unsigned int)c1.w << 16);
        a2.x += __uint_as_float((unsigned int)c2.x << 16);
        a2.y += __uint_as_float((unsigned int)c2.y << 16);
        a2.z += __uint_as_float((unsigned int)c2.z << 16);
        a2.w += __uint_as_float((unsigned int)c2.w << 16);
        a3.x += __uint_as_float((unsigned int)c3.x << 16);
        a3.y += __uint_as_float((unsigned int)c3.y << 16);
        a3.z += __uint_as_float((unsigned int)c3.z << 16);
        a3.w += __uint_as_float((unsigned int)c3.w << 16);
      }
      for (; idx < n; ++idx) {
        const int j = list[idx];
        const ushort4 c = *(const ushort4*)(cT + ((size_t)j << 12) + t * 4);
        a0.x += __uint_as_float((unsigned int)c.x << 16);
        a0.y += __uint_as_float((unsigned int)c.y << 16);
        a0.z += __uint_as_float((unsigned int)c.z << 16);
        a0.w += __uint_as_float((unsigned int)c.w << 16);
      }
    } else {
      const float* conn = (const float*)connv;
      for (int idx = 0; idx < n; ++idx) {
        const int j = list[idx];
        a0.x += conn[(size_t)(t * 4 + 0) * N_NODES + j];
        a0.y += conn[(size_t)(t * 4 + 1) * N_NODES + j];
        a0.z += conn[(size_t)(t * 4 + 2) * N_NODES + j];
        a0.w += conn[(size_t)(t * 4 + 3) * N_NODES + j];
      }
    }
    const float4 acc = make_float4((a0.x + a1.x) + (a2.x + a3.x),
                                   (a0.y + a1.y) + (a2.y + a3.y),
                                   (a0.z + a1.z) + (a2.z + a3.z),
                                   (a0.w + a1.w) + (a2.w + a3.w));

    s.x = (v0 > 1.0f) ? 0.0f : 0.9f * v0 + acc.x;
    s.y = (v1 > 1.0f) ? 0.0f : 0.9f * v1 + acc.y;
    s.z = (v2 > 1.0f) ? 0.0f : 0.9f * v2 + acc.z;
    s.w = (v3 > 1.0f) ? 0.0f : 0.9f * v3 + acc.w;
  }

  *(float4*)(out + (size_t)b * N_NODES + t * 4) = s;
  if (t == 0) atomicMax(maxslot, __float_as_uint(total));  // totals >= 0
}

// ---------------------------------------------------------------------------
extern "C" void kernel_launch(void* const* d_in, const int* in_sizes, int n_in,
                              void* d_out, int out_size, void* d_ws, size_t ws_size,
                              hipStream_t stream) {
  const float* input = (const float*)d_in[0];  // [128,4096]
  const float* W     = (const float*)d_in[1];  // [4096,4096]
  const float* bias  = (const float*)d_in[2];  // [4096]
  const float* conn  = (const float*)d_in[3];  // [4096,4096]
  float* out = (float*)d_out;                  // [128*4096] state + [1] max_size

  const size_t connT_bytes = (size_t)N_NODES * N_NODES * sizeof(unsigned short);  // 32 MB
  const size_t part_bytes  = (size_t)SPLITK * BATCH * N_NODES * sizeof(float);    // 32 MB
  unsigned int* maxslot = (unsigned int*)(out + (size_t)BATCH * N_NODES);

  hipMemsetAsync(maxslot, 0, sizeof(unsigned int), stream);

  if (ws_size >= connT_bytes + part_bytes) {
    unsigned short* connT = (unsigned short*)d_ws;
    float* part = (float*)((char*)d_ws + connT_bytes);
    transpose_bf16_kernel<<<dim3(128, 128), 256, 0, stream>>>(conn, connT);
    proj_gemm_mfma<SPLITK><<<dim3(N_NODES / GBN, SPLITK), 256, 0, stream>>>(input, W, part);
    avalanche_kernel<1, SPLITK><<<BATCH, 1024, 0, stream>>>(part, bias, connT, out, maxslot);
  } else {
    // Fallback: no workspace — f32 GEMM into d_out, in-place bias, strided gather.
    proj_gemm_valu<<<dim3(N_NODES / 64, 1), 256, 0, stream>>>(input, W, out);
    bias_inplace_kernel<<<BATCH * N_NODES / 1024, 256, 0, stream>>>(out, bias);
    avalanche_kernel<0, 1><<<BATCH, 1024, 0, stream>>>(out, nullptr, conn, out, maxslot);
  }
}

// Round 5
// 75.791 us; speedup vs baseline: 4.0689x; 1.1563x over previous
//
#include <hip/hip_runtime.h>

#define N_NODES 4096
#define BATCH 128
#define SPLITK 16
#define GBN 64  // GEMM N-tile

typedef _Float16 f16x4 __attribute__((ext_vector_type(4)));
typedef _Float16 f16x8 __attribute__((ext_vector_type(8)));
typedef float f32x4 __attribute__((ext_vector_type(4)));

// fp8 connT if the HW cvt builtins exist; else bf16 connT.
#if defined(__has_builtin)
#if __has_builtin(__builtin_amdgcn_cvt_f32_fp8) && __has_builtin(__builtin_amdgcn_cvt_pk_fp8_f32)
#define CONN_FP8 1
#endif
#endif
#ifndef CONN_FP8
#define CONN_FP8 0
#endif

#if CONN_FP8
#define CONN_ELEM_BYTES 1
#define CONN_SCALE (1.0f / 256.0f)
#else
#define CONN_ELEM_BYTES 2
#define CONN_SCALE 1.0f
#endif

__device__ __forceinline__ void conn_store(void* out, size_t off, float v) {
#if CONN_FP8
  ((unsigned char*)out)[off] =
      (unsigned char)(__builtin_amdgcn_cvt_pk_fp8_f32(v * 256.0f, 0.0f, 0, false) & 0xff);
#else
  const unsigned int u = __float_as_uint(v);
  ((unsigned short*)out)[off] = (unsigned short)((u + 0x7FFFu + ((u >> 16) & 1u)) >> 16);  // RNE
#endif
}

// 4 consecutive conn values of row j at node offset t*4 (t = thread id)
__device__ __forceinline__ float4 conn_load4(const void* cT, int j, int t) {
#if CONN_FP8
  const unsigned int c = *(const unsigned int*)((const unsigned char*)cT + ((size_t)j << 12) + t * 4);
  return make_float4(__builtin_amdgcn_cvt_f32_fp8(c, 0), __builtin_amdgcn_cvt_f32_fp8(c, 1),
                     __builtin_amdgcn_cvt_f32_fp8(c, 2), __builtin_amdgcn_cvt_f32_fp8(c, 3));
#else
  const ushort4 c = *(const ushort4*)((const unsigned short*)cT + ((size_t)j << 12) + t * 4);
  return make_float4(__uint_as_float((unsigned int)c.x << 16),
                     __uint_as_float((unsigned int)c.y << 16),
                     __uint_as_float((unsigned int)c.z << 16),
                     __uint_as_float((unsigned int)c.w << 16));
#endif
}

// ---------------------------------------------------------------------------
// connT[j][i] = enc(conn[i][j])
// ---------------------------------------------------------------------------
__global__ __launch_bounds__(256) void transpose_conn_kernel(const float* __restrict__ in,
                                                             void* __restrict__ out) {
  __shared__ float tile[32][33];
  const int bx = blockIdx.x, by = blockIdx.y;
  const int tx = threadIdx.x & 31;
  const int ty = threadIdx.x >> 5;  // 0..7
#pragma unroll
  for (int j = 0; j < 4; ++j) {
    const int r = ty + j * 8;
    tile[r][tx] = in[(size_t)(by * 32 + r) * N_NODES + bx * 32 + tx];
  }
  __syncthreads();
#pragma unroll
  for (int j = 0; j < 4; ++j) {
    const int r = ty + j * 8;
    conn_store(out, (size_t)(bx * 32 + r) * N_NODES + by * 32 + tx, tile[tx][r]);
  }
}

// ---------------------------------------------------------------------------
// Split-f16 MFMA GEMM with 2-phase register prefetch.
// P[s][m][n] = sum_{k in chunk s} A[m][k]*W[n][k] via Ah*Bh + Ah*Bl + Al*Bh.
// A pre-scaled x256, W x64; epilogue x2^-14. BM=128, BN=64, BK=32, 4 waves.
// ---------------------------------------------------------------------------
template <int NSPLIT>
__global__ __launch_bounds__(256) void proj_gemm_mfma(const float* __restrict__ A,
                                                      const float* __restrict__ W,
                                                      float* __restrict__ P) {
  constexpr int KC = N_NODES / NSPLIT;  // 256 for NSPLIT=16 (power of 2)
  constexpr int PITCH = 40;             // f16 per LDS row (32 + 8 pad)
  __shared__ alignas(16) _Float16 Ah[128 * PITCH], Al[128 * PITCH];
  __shared__ alignas(16) _Float16 Bh[GBN * PITCH], Bl[GBN * PITCH];

  const int tid = threadIdx.x;
  const int wave = tid >> 6, lane = tid & 63;
  const int wm = wave >> 1, wn = wave & 1;    // 2x2 wave grid
  const int g = lane >> 4, lrow = lane & 15;  // frag lane coords
  const int n0 = blockIdx.x * GBN;
  const int kb = blockIdx.y * KC;
  const int scol = (tid & 7) * 4;  // staging k-offset (float4)
  const int srow = tid >> 3;       // 0..31

  const float* Abase = A + (size_t)srow * N_NODES + kb + scol;
  const float* Wbase = W + (size_t)(n0 + srow) * N_NODES + kb + scol;

  f32x4 acc[4][2] = {};

  // prologue: load tile k2=0 into registers
  float4 av[4], wv[2];
#pragma unroll
  for (int r = 0; r < 4; ++r) av[r] = *(const float4*)(Abase + (size_t)(r * 32) * N_NODES);
#pragma unroll
  for (int r = 0; r < 2; ++r) wv[r] = *(const float4*)(Wbase + (size_t)(r * 32) * N_NODES);

  for (int k2 = 0; k2 < KC; k2 += 32) {
    __syncthreads();  // previous iteration's LDS readers done
    // phase 1: convert current regs -> LDS (split hi/lo f16)
#pragma unroll
    for (int r = 0; r < 4; ++r) {
      const int row = srow + r * 32;
      f16x4 hi, lo;
      const float x0 = av[r].x * 256.f, x1 = av[r].y * 256.f,
                  x2 = av[r].z * 256.f, x3 = av[r].w * 256.f;
      hi[0] = (_Float16)x0; lo[0] = (_Float16)(x0 - (float)hi[0]);
      hi[1] = (_Float16)x1; lo[1] = (_Float16)(x1 - (float)hi[1]);
      hi[2] = (_Float16)x2; lo[2] = (_Float16)(x2 - (float)hi[2]);
      hi[3] = (_Float16)x3; lo[3] = (_Float16)(x3 - (float)hi[3]);
      *(f16x4*)&Ah[row * PITCH + scol] = hi;
      *(f16x4*)&Al[row * PITCH + scol] = lo;
    }
#pragma unroll
    for (int r = 0; r < 2; ++r) {
      const int row = srow + r * 32;
      f16x4 hi, lo;
      const float x0 = wv[r].x * 64.f, x1 = wv[r].y * 64.f,
                  x2 = wv[r].z * 64.f, x3 = wv[r].w * 64.f;
      hi[0] = (_Float16)x0; lo[0] = (_Float16)(x0 - (float)hi[0]);
      hi[1] = (_Float16)x1; lo[1] = (_Float16)(x1 - (float)hi[1]);
      hi[2] = (_Float16)x2; lo[2] = (_Float16)(x2 - (float)hi[2]);
      hi[3] = (_Float16)x3; lo[3] = (_Float16)(x3 - (float)hi[3]);
      *(f16x4*)&Bh[row * PITCH + scol] = hi;
      *(f16x4*)&Bl[row * PITCH + scol] = lo;
    }
    __syncthreads();

    // phase 2: issue NEXT tile's loads (wrap on last iter; redundant but cheap),
    // then fragment reads + MFMA hide their latency.
    const int knext = (k2 + 32) & (KC - 1);
#pragma unroll
    for (int r = 0; r < 4; ++r)
      av[r] = *(const float4*)(Abase + (size_t)(r * 32) * N_NODES + knext);
#pragma unroll
    for (int r = 0; r < 2; ++r)
      wv[r] = *(const float4*)(Wbase + (size_t)(r * 32) * N_NODES + knext);

    f16x8 ah[4], al[4], bh[2], bl[2];
#pragma unroll
    for (int fm = 0; fm < 4; ++fm) {
      const int m = wm * 64 + fm * 16 + lrow;
      ah[fm] = *(const f16x8*)&Ah[m * PITCH + g * 8];
      al[fm] = *(const f16x8*)&Al[m * PITCH + g * 8];
    }
#pragma unroll
    for (int fn = 0; fn < 2; ++fn) {
      const int n = wn * 32 + fn * 16 + lrow;
      bh[fn] = *(const f16x8*)&Bh[n * PITCH + g * 8];
      bl[fn] = *(const f16x8*)&Bl[n * PITCH + g * 8];
    }
#pragma unroll
    for (int fm = 0; fm < 4; ++fm)
#pragma unroll
      for (int fn = 0; fn < 2; ++fn) {
        acc[fm][fn] = __builtin_amdgcn_mfma_f32_16x16x32_f16(ah[fm], bh[fn], acc[fm][fn], 0, 0, 0);
        acc[fm][fn] = __builtin_amdgcn_mfma_f32_16x16x32_f16(ah[fm], bl[fn], acc[fm][fn], 0, 0, 0);
        acc[fm][fn] = __builtin_amdgcn_mfma_f32_16x16x32_f16(al[fm], bh[fn], acc[fm][fn], 0, 0, 0);
      }
  }

  // epilogue: D row = (lane>>4)*4 + reg, col = lane&15 (HW-verified layout)
  constexpr float INV = 1.0f / 16384.0f;  // 1/(256*64)
  float* Pbase = P + (size_t)blockIdx.y * BATCH * N_NODES;
#pragma unroll
  for (int fm = 0; fm < 4; ++fm)
#pragma unroll
    for (int fn = 0; fn < 2; ++fn) {
      const int n = n0 + wn * 32 + fn * 16 + lrow;
#pragma unroll
      for (int reg = 0; reg < 4; ++reg) {
        const int m = wm * 64 + fm * 16 + g * 4 + reg;
        Pbase[(size_t)m * N_NODES + n] = acc[fm][fn][reg] * INV;
      }
    }
}

// ---------------------------------------------------------------------------
// Fallback-only f32 VALU GEMM (no workspace): P[m][n] = sum_k A[m][k]*W[n][k]
// ---------------------------------------------------------------------------
__global__ __launch_bounds__(256) void proj_gemm_valu(const float* __restrict__ A,
                                                      const float* __restrict__ W,
                                                      float* __restrict__ P) {
  __shared__ float As[16][132];
  __shared__ float Bs[16][68];
  const int tid = threadIdx.x;
  const int n0 = blockIdx.x * 64;
  const int tx = tid & 15, ty = tid >> 4;
  const int arow = tid >> 1, acol = (tid & 1) * 8;
  const int brow = tid >> 2, bcol = (tid & 3) * 4;
  float acc[2][4][4] = {};
  const float* Aptr = A + (size_t)arow * N_NODES + acol;
  const float* Wptr = W + (size_t)(n0 + brow) * N_NODES + bcol;
  for (int k0 = 0; k0 < N_NODES; k0 += 16) {
    const float4 a0 = *(const float4*)(Aptr + k0);
    const float4 a1 = *(const float4*)(Aptr + k0 + 4);
    const float4 bv = *(const float4*)(Wptr + k0);
    __syncthreads();
    As[acol + 0][arow] = a0.x; As[acol + 1][arow] = a0.y;
    As[acol + 2][arow] = a0.z; As[acol + 3][arow] = a0.w;
    As[acol + 4][arow] = a1.x; As[acol + 5][arow] = a1.y;
    As[acol + 6][arow] = a1.z; As[acol + 7][arow] = a1.w;
    Bs[bcol + 0][brow] = bv.x; Bs[bcol + 1][brow] = bv.y;
    Bs[bcol + 2][brow] = bv.z; Bs[bcol + 3][brow] = bv.w;
    __syncthreads();
#pragma unroll
    for (int kk = 0; kk < 16; ++kk) {
      const float4 av0 = *(const float4*)&As[kk][ty * 4];
      const float4 av1 = *(const float4*)&As[kk][64 + ty * 4];
      const float4 bv4 = *(const float4*)&Bs[kk][tx * 4];
      const float am[8] = {av0.x, av0.y, av0.z, av0.w, av1.x, av1.y, av1.z, av1.w};
      const float bn[4] = {bv4.x, bv4.y, bv4.z, bv4.w};
#pragma unroll
      for (int i2 = 0; i2 < 2; ++i2)
#pragma unroll
        for (int i = 0; i < 4; ++i)
#pragma unroll
          for (int j = 0; j < 4; ++j)
            acc[i2][i][j] += am[i2 * 4 + i] * bn[j];
    }
  }
#pragma unroll
  for (int i2 = 0; i2 < 2; ++i2)
#pragma unroll
    for (int i = 0; i < 4; ++i) {
      const int m = i2 * 64 + ty * 4 + i;
      *(float4*)(P + (size_t)m * N_NODES + n0 + tx * 4) =
          make_float4(acc[i2][i][0], acc[i2][i][1], acc[i2][i][2], acc[i2][i][3]);
    }
}

__global__ __launch_bounds__(256) void bias_inplace_kernel(float* __restrict__ P,
                                                           const float* __restrict__ bias) {
  const size_t base = ((size_t)blockIdx.x * 256 + threadIdx.x) * 4;
  const int n = (int)(base & (N_NODES - 1));
  float4 s = *(const float4*)(P + base);
  const float4 bv = *(const float4*)(bias + n);
  s.x += bv.x; s.y += bv.y; s.z += bv.z; s.w += bv.w;
  *(float4*)(P + base) = s;
}

// ---------------------------------------------------------------------------
// One workgroup per sample; state in registers (1024 thr x float4).
// MODE 1: prologue reduces NSPLIT GEMM partials + bias; ordered active-list
//         gather over encoded connT rows, 8-way unrolled.
// MODE 0: proj precomputed; f32 conn column gather (fallback).
// ---------------------------------------------------------------------------
template <int MODE, int NSPLIT>
__global__ __launch_bounds__(1024) void avalanche_kernel(const float* __restrict__ Pin,
                                                         const float* __restrict__ bias,
                                                         const void* __restrict__ connv,
                                                         float* __restrict__ out,
                                                         unsigned int* __restrict__ maxslot) {
  const int b = blockIdx.x;
  const int t = threadIdx.x;
  __shared__ unsigned long long mask[64];
  __shared__ int wincl[64];
  __shared__ int list[N_NODES];

  float4 s;
  if (MODE == 1) {
    const float4 bv = *(const float4*)(bias + t * 4);
    s = bv;
#pragma unroll
    for (int sp = 0; sp < NSPLIT; ++sp) {
      const float4 v = *(const float4*)(Pin + (size_t)sp * BATCH * N_NODES +
                                        (size_t)b * N_NODES + t * 4);
      s.x += v.x; s.y += v.y; s.z += v.z; s.w += v.w;
    }
  } else {
    s = *(const float4*)(Pin + (size_t)b * N_NODES + t * 4);
  }

  float total = 0.0f;

  for (int it = 0; it < 100; ++it) {
    const float v0 = s.x, v1 = s.y, v2 = s.z, v3 = s.w;
    unsigned int bits = 0;
    if (v0 > 1.0f) bits |= 1u;
    if (v1 > 1.0f) bits |= 2u;
    if (v2 > 1.0f) bits |= 4u;
    if (v3 > 1.0f) bits |= 8u;

    __syncthreads();
    if (t < 64) mask[t] = 0ULL;
    __syncthreads();
    if (bits) atomicOr(&mask[t >> 4], (unsigned long long)bits << ((t & 15) * 4));
    __syncthreads();

    if (t < 64) {
      int incl = __popcll(mask[t]);
#pragma unroll
      for (int d = 1; d < 64; d <<= 1) {
        const int y = __shfl_up(incl, d);
        if (t >= d) incl += y;
      }
      wincl[t] = incl;
    }
    __syncthreads();
    const int n = wincl[63];
    if (n == 0) break;  // sticky done: state frozen
    total += (float)n;

    if (t < 64) {
      unsigned long long m = mask[t];
      int o = wincl[t] - __popcll(m);
      while (m) {
        list[o++] = (t << 6) + __builtin_ctzll(m);
        m &= m - 1;
      }
    }
    __syncthreads();

    float4 a0 = make_float4(0.f, 0.f, 0.f, 0.f), a1 = a0, a2 = a0, a3 = a0;
    if (MODE == 1) {
      int idx = 0;
      for (; idx + 8 <= n; idx += 8) {
        const float4 c0 = conn_load4(connv, list[idx + 0], t);
        const float4 c1 = conn_load4(connv, list[idx + 1], t);
        const float4 c2 = conn_load4(connv, list[idx + 2], t);
        const float4 c3 = conn_load4(connv, list[idx + 3], t);
        const float4 c4 = conn_load4(connv, list[idx + 4], t);
        const float4 c5 = conn_load4(connv, list[idx + 5], t);
        const float4 c6 = conn_load4(connv, list[idx + 6], t);
        const float4 c7 = conn_load4(connv, list[idx + 7], t);
        a0.x += c0.x; a0.y += c0.y; a0.z += c0.z; a0.w += c0.w;
        a1.x += c1.x; a1.y += c1.y; a1.z += c1.z; a1.w += c1.w;
        a2.x += c2.x; a2.y += c2.y; a2.z += c2.z; a2.w += c2.w;
        a3.x += c3.x; a3.y += c3.y; a3.z += c3.z; a3.w += c3.w;
        a0.x += c4.x; a0.y += c4.y; a0.z += c4.z; a0.w += c4.w;
        a1.x += c5.x; a1.y += c5.y; a1.z += c5.z; a1.w += c5.w;
        a2.x += c6.x; a2.y += c6.y; a2.z += c6.z; a2.w += c6.w;
        a3.x += c7.x; a3.y += c7.y; a3.z += c7.z; a3.w += c7.w;
      }
      for (; idx < n; ++idx) {
        const float4 c = conn_load4(connv, list[idx], t);
        a0.x += c.x; a0.y += c.y; a0.z += c.z; a0.w += c.w;
      }
    } else {
      const float* conn = (const float*)connv;
      for (int idx = 0; idx < n; ++idx) {
        const int j = list[idx];
        a0.x += conn[(size_t)(t * 4 + 0) * N_NODES + j];
        a0.y += conn[(size_t)(t * 4 + 1) * N_NODES + j];
        a0.z += conn[(size_t)(t * 4 + 2) * N_NODES + j];
        a0.w += conn[(size_t)(t * 4 + 3) * N_NODES + j];
      }
    }
    const float sc = (MODE == 1) ? CONN_SCALE : 1.0f;
    const float4 acc = make_float4(((a0.x + a1.x) + (a2.x + a3.x)) * sc,
                                   ((a0.y + a1.y) + (a2.y + a3.y)) * sc,
                                   ((a0.z + a1.z) + (a2.z + a3.z)) * sc,
                                   ((a0.w + a1.w) + (a2.w + a3.w)) * sc);

    s.x = (v0 > 1.0f) ? 0.0f : 0.9f * v0 + acc.x;
    s.y = (v1 > 1.0f) ? 0.0f : 0.9f * v1 + acc.y;
    s.z = (v2 > 1.0f) ? 0.0f : 0.9f * v2 + acc.z;
    s.w = (v3 > 1.0f) ? 0.0f : 0.9f * v3 + acc.w;
  }

  *(float4*)(out + (size_t)b * N_NODES + t * 4) = s;
  if (t == 0) atomicMax(maxslot, __float_as_uint(total));  // totals >= 0
}

// ---------------------------------------------------------------------------
extern "C" void kernel_launch(void* const* d_in, const int* in_sizes, int n_in,
                              void* d_out, int out_size, void* d_ws, size_t ws_size,
                              hipStream_t stream) {
  const float* input = (const float*)d_in[0];  // [128,4096]
  const float* W     = (const float*)d_in[1];  // [4096,4096]
  const float* bias  = (const float*)d_in[2];  // [4096]
  const float* conn  = (const float*)d_in[3];  // [4096,4096]
  float* out = (float*)d_out;                  // [128*4096] state + [1] max_size

  const size_t connT_bytes = (size_t)N_NODES * N_NODES * CONN_ELEM_BYTES;
  const size_t part_bytes  = (size_t)SPLITK * BATCH * N_NODES * sizeof(float);  // 32 MB
  unsigned int* maxslot = (unsigned int*)(out + (size_t)BATCH * N_NODES);

  hipMemsetAsync(maxslot, 0, sizeof(unsigned int), stream);

  if (ws_size >= connT_bytes + part_bytes) {
    void* connT = d_ws;
    float* part = (float*)((char*)d_ws + connT_bytes);
    transpose_conn_kernel<<<dim3(128, 128), 256, 0, stream>>>(conn, connT);
    proj_gemm_mfma<SPLITK><<<dim3(N_NODES / GBN, SPLITK), 256, 0, stream>>>(input, W, part);
    avalanche_kernel<1, SPLITK><<<BATCH, 1024, 0, stream>>>(part, bias, connT, out, maxslot);
  } else {
    // Fallback: no workspace — f32 GEMM into d_out, in-place bias, strided gather.
    proj_gemm_valu<<<dim3(N_NODES / 64, 1), 256, 0, stream>>>(input, W, out);
    bias_inplace_kernel<<<BATCH * N_NODES / 1024, 256, 0, stream>>>(out, bias);
    avalanche_kernel<0, 1><<<BATCH, 1024, 0, stream>>>(out, nullptr, conn, out, maxslot);
  }
}

// Round 6
// 64.358 us; speedup vs baseline: 4.7918x; 1.1776x over previous
//
#include <hip/hip_runtime.h>

#define N_NODES 4096
#define BATCH 128
#define SPLITK 8
#define GBN 32                       // GEMM N-tile
#define PITCH 40                     // f16 per LDS row (32 + 8 pad; 80B rows keep b128 aligned, 2-way banks)
#define KCHUNK (N_NODES / SPLITK)    // 512
#define NIT (KCHUNK / 32)            // 16
#define GEMM_BLOCKS ((N_NODES / GBN) * SPLITK)  // 1024
#define TRANS_BLOCKS (64 * 64)                  // 4096 64x64 tiles

typedef _Float16 f16x4 __attribute__((ext_vector_type(4)));
typedef _Float16 f16x8 __attribute__((ext_vector_type(8)));
typedef float f32x4 __attribute__((ext_vector_type(4)));

// fp8 connT if the HW cvt builtins exist; else bf16 connT.
#if defined(__has_builtin)
#if __has_builtin(__builtin_amdgcn_cvt_f32_fp8) && __has_builtin(__builtin_amdgcn_cvt_pk_fp8_f32)
#define CONN_FP8 1
#endif
#endif
#ifndef CONN_FP8
#define CONN_FP8 0
#endif

#if CONN_FP8
#define CONN_ELEM_BYTES 1
#define CONN_SCALE (1.0f / 256.0f)
#else
#define CONN_ELEM_BYTES 2
#define CONN_SCALE 1.0f
#endif

__device__ __forceinline__ void conn_store4(void* out, size_t off, float4 v) {
#if CONN_FP8
  unsigned int p = __builtin_amdgcn_cvt_pk_fp8_f32(v.x * 256.0f, v.y * 256.0f, 0, false);
  p = (unsigned int)__builtin_amdgcn_cvt_pk_fp8_f32(v.z * 256.0f, v.w * 256.0f, (int)p, true);
  *(unsigned int*)((unsigned char*)out + off) = p;
#else
  const unsigned int ux = __float_as_uint(v.x), uy = __float_as_uint(v.y);
  const unsigned int uz = __float_as_uint(v.z), uw = __float_as_uint(v.w);
  ushort4 u;
  u.x = (unsigned short)((ux + 0x7FFFu + ((ux >> 16) & 1u)) >> 16);  // RNE
  u.y = (unsigned short)((uy + 0x7FFFu + ((uy >> 16) & 1u)) >> 16);
  u.z = (unsigned short)((uz + 0x7FFFu + ((uz >> 16) & 1u)) >> 16);
  u.w = (unsigned short)((uw + 0x7FFFu + ((uw >> 16) & 1u)) >> 16);
  *(ushort4*)((unsigned short*)out + off) = u;
#endif
}

// 4 consecutive conn values of row j at node offset t*4 (t = thread id)
__device__ __forceinline__ float4 conn_load4(const void* cT, int j, int t) {
#if CONN_FP8
  const unsigned int c = *(const unsigned int*)((const unsigned char*)cT + ((size_t)j << 12) + t * 4);
  return make_float4(__builtin_amdgcn_cvt_f32_fp8(c, 0), __builtin_amdgcn_cvt_f32_fp8(c, 1),
                     __builtin_amdgcn_cvt_f32_fp8(c, 2), __builtin_amdgcn_cvt_f32_fp8(c, 3));
#else
  const ushort4 c = *(const ushort4*)((const unsigned short*)cT + ((size_t)j << 12) + t * 4);
  return make_float4(__uint_as_float((unsigned int)c.x << 16),
                     __uint_as_float((unsigned int)c.y << 16),
                     __uint_as_float((unsigned int)c.z << 16),
                     __uint_as_float((unsigned int)c.w << 16));
#endif
}

// ---------------------------------------------------------------------------
// Fused prep kernel. Blocks [0, GEMM_BLOCKS): split-f16 MFMA split-K GEMM
// (latency-structured). Blocks [GEMM_BLOCKS, +TRANS_BLOCKS): connT transpose
// (BW-bound) — complementary, overlap on the machine.
// ---------------------------------------------------------------------------
struct GemmSmem {
  alignas(16) _Float16 Ah[2][128 * PITCH];
  alignas(16) _Float16 Al[2][128 * PITCH];
  alignas(16) _Float16 Bh[2][GBN * PITCH];
  alignas(16) _Float16 Bl[2][GBN * PITCH];
};
struct TransSmem { float tile[64][65]; };
union PrepSmem { GemmSmem g; TransSmem t; };

__global__ __launch_bounds__(256) void fused_prep_kernel(const float* __restrict__ A,
                                                         const float* __restrict__ W,
                                                         const float* __restrict__ conn,
                                                         float* __restrict__ P,
                                                         void* __restrict__ connT,
                                                         unsigned int* __restrict__ maxslot) {
  __shared__ PrepSmem sm;
  const int tid = threadIdx.x;
  const int bid = blockIdx.x;

  if (bid < GEMM_BLOCKS) {
    // ---------------- GEMM role ----------------
    if (bid == 0 && tid == 0) *maxslot = 0u;
    const int wave = tid >> 6, lane = tid & 63;
    const int wm = wave >> 1, wn = wave & 1;    // 2x2 wave grid: 64 rows x 16 cols each
    const int g = lane >> 4, lrow = lane & 15;  // frag lane coords
    const int n0 = (bid & 127) * GBN;
    const int kb = (bid >> 7) * KCHUNK;
    const int srow = tid >> 3;       // 0..31
    const int scol = (tid & 7) * 4;  // k sub-offset (float4)

    const float* Abase = A + (size_t)srow * N_NODES + kb + scol;
    const float* Wbase = W + (size_t)(n0 + srow) * N_NODES + kb + scol;

    f32x4 acc[4] = {};
    float4 avA[4], avB[4], wvA, wvB;
#pragma unroll
    for (int r = 0; r < 4; ++r) avA[r] = *(const float4*)(Abase + (size_t)(r * 32) * N_NODES);
    wvA = *(const float4*)Wbase;
#pragma unroll
    for (int r = 0; r < 4; ++r) avB[r] = *(const float4*)(Abase + (size_t)(r * 32) * N_NODES + 32);
    wvB = *(const float4*)(Wbase + 32);

    // one tile step: convert regs -> LDS[buf]; refill regs with tile it+2;
    // single barrier; ds_read frags; 12 MFMA. (dbuf proof: reads of buf at
    // iter t-1 complete before barrier(t); writes to buf resume at t+1.)
    auto step = [&](float4 (&av)[4], float4& wv, int buf, int it) {
#pragma unroll
      for (int r = 0; r < 4; ++r) {
        const int row = srow + r * 32;
        f16x4 hi, lo;
        const float x0 = av[r].x * 256.f, x1 = av[r].y * 256.f,
                    x2 = av[r].z * 256.f, x3 = av[r].w * 256.f;
        hi[0] = (_Float16)x0; lo[0] = (_Float16)(x0 - (float)hi[0]);
        hi[1] = (_Float16)x1; lo[1] = (_Float16)(x1 - (float)hi[1]);
        hi[2] = (_Float16)x2; lo[2] = (_Float16)(x2 - (float)hi[2]);
        hi[3] = (_Float16)x3; lo[3] = (_Float16)(x3 - (float)hi[3]);
        *(f16x4*)&sm.g.Ah[buf][row * PITCH + scol] = hi;
        *(f16x4*)&sm.g.Al[buf][row * PITCH + scol] = lo;
      }
      {
        f16x4 hi, lo;
        const float x0 = wv.x * 64.f, x1 = wv.y * 64.f, x2 = wv.z * 64.f, x3 = wv.w * 64.f;
        hi[0] = (_Float16)x0; lo[0] = (_Float16)(x0 - (float)hi[0]);
        hi[1] = (_Float16)x1; lo[1] = (_Float16)(x1 - (float)hi[1]);
        hi[2] = (_Float16)x2; lo[2] = (_Float16)(x2 - (float)hi[2]);
        hi[3] = (_Float16)x3; lo[3] = (_Float16)(x3 - (float)hi[3]);
        *(f16x4*)&sm.g.Bh[buf][srow * PITCH + scol] = hi;
        *(f16x4*)&sm.g.Bl[buf][srow * PITCH + scol] = lo;
      }
      // depth-2 prefetch: issue tile it+2 (wraps harmlessly on the tail)
      const int knext = ((it + 2) * 32) & (KCHUNK - 1);
#pragma unroll
      for (int r = 0; r < 4; ++r)
        av[r] = *(const float4*)(Abase + (size_t)(r * 32) * N_NODES + knext);
      wv = *(const float4*)(Wbase + knext);

      __syncthreads();

      f16x8 ah[4], al[4], bh, bl;
#pragma unroll
      for (int fm = 0; fm < 4; ++fm) {
        const int m = wm * 64 + fm * 16 + lrow;
        ah[fm] = *(const f16x8*)&sm.g.Ah[buf][m * PITCH + g * 8];
        al[fm] = *(const f16x8*)&sm.g.Al[buf][m * PITCH + g * 8];
      }
      const int nn = wn * 16 + lrow;
      bh = *(const f16x8*)&sm.g.Bh[buf][nn * PITCH + g * 8];
      bl = *(const f16x8*)&sm.g.Bl[buf][nn * PITCH + g * 8];
#pragma unroll
      for (int fm = 0; fm < 4; ++fm) {
        acc[fm] = __builtin_amdgcn_mfma_f32_16x16x32_f16(ah[fm], bh, acc[fm], 0, 0, 0);
        acc[fm] = __builtin_amdgcn_mfma_f32_16x16x32_f16(ah[fm], bl, acc[fm], 0, 0, 0);
        acc[fm] = __builtin_amdgcn_mfma_f32_16x16x32_f16(al[fm], bh, acc[fm], 0, 0, 0);
      }
    };

#pragma unroll
    for (int it = 0; it < NIT; it += 2) {
      step(avA, wvA, 0, it);
      step(avB, wvB, 1, it + 1);
    }

    // epilogue: D row = (lane>>4)*4 + reg, col = lane&15 (HW-verified)
    constexpr float INV = 1.0f / 16384.0f;  // 1/(256*64)
    float* Pb = P + (size_t)(bid >> 7) * BATCH * N_NODES;
    const int n = n0 + wn * 16 + lrow;
#pragma unroll
    for (int fm = 0; fm < 4; ++fm)
#pragma unroll
      for (int reg = 0; reg < 4; ++reg) {
        const int m = wm * 64 + fm * 16 + g * 4 + reg;
        Pb[(size_t)m * N_NODES + n] = acc[fm][reg] * INV;
      }
  } else {
    // ---------------- transpose role: connT[j][i] = enc(conn[i][j]) ----------
    const int idx = bid - GEMM_BLOCKS;
    const int bx = idx & 63, by = idx >> 6;  // 64x64 tile coords
    const int tx = tid & 15, ty = tid >> 4;  // 16 x 16
#pragma unroll
    for (int r = 0; r < 4; ++r) {
      const float4 v =
          *(const float4*)(conn + (size_t)(by * 64 + ty + 16 * r) * N_NODES + bx * 64 + tx * 4);
      sm.t.tile[ty + 16 * r][tx * 4 + 0] = v.x;
      sm.t.tile[ty + 16 * r][tx * 4 + 1] = v.y;
      sm.t.tile[ty + 16 * r][tx * 4 + 2] = v.z;
      sm.t.tile[ty + 16 * r][tx * 4 + 3] = v.w;
    }
    __syncthreads();
#pragma unroll
    for (int r = 0; r < 4; ++r) {
      const int orow = ty + 16 * r;
      float4 v;
      v.x = sm.t.tile[tx * 4 + 0][orow];
      v.y = sm.t.tile[tx * 4 + 1][orow];
      v.z = sm.t.tile[tx * 4 + 2][orow];
      v.w = sm.t.tile[tx * 4 + 3][orow];
      conn_store4(connT, (size_t)(bx * 64 + orow) * N_NODES + by * 64 + tx * 4, v);
    }
  }
}

// ---------------------------------------------------------------------------
// Fallback-only f32 VALU GEMM (no workspace): P[m][n] = sum_k A[m][k]*W[n][k]
// ---------------------------------------------------------------------------
__global__ __launch_bounds__(256) void proj_gemm_valu(const float* __restrict__ A,
                                                      const float* __restrict__ W,
                                                      float* __restrict__ P,
                                                      unsigned int* __restrict__ maxslot) {
  if (blockIdx.x == 0 && threadIdx.x == 0) *maxslot = 0u;
  __shared__ float As[16][132];
  __shared__ float Bs[16][68];
  const int tid = threadIdx.x;
  const int n0 = blockIdx.x * 64;
  const int tx = tid & 15, ty = tid >> 4;
  const int arow = tid >> 1, acol = (tid & 1) * 8;
  const int brow = tid >> 2, bcol = (tid & 3) * 4;
  float acc[2][4][4] = {};
  const float* Aptr = A + (size_t)arow * N_NODES + acol;
  const float* Wptr = W + (size_t)(n0 + brow) * N_NODES + bcol;
  for (int k0 = 0; k0 < N_NODES; k0 += 16) {
    const float4 a0 = *(const float4*)(Aptr + k0);
    const float4 a1 = *(const float4*)(Aptr + k0 + 4);
    const float4 bv = *(const float4*)(Wptr + k0);
    __syncthreads();
    As[acol + 0][arow] = a0.x; As[acol + 1][arow] = a0.y;
    As[acol + 2][arow] = a0.z; As[acol + 3][arow] = a0.w;
    As[acol + 4][arow] = a1.x; As[acol + 5][arow] = a1.y;
    As[acol + 6][arow] = a1.z; As[acol + 7][arow] = a1.w;
    Bs[bcol + 0][brow] = bv.x; Bs[bcol + 1][brow] = bv.y;
    Bs[bcol + 2][brow] = bv.z; Bs[bcol + 3][brow] = bv.w;
    __syncthreads();
#pragma unroll
    for (int kk = 0; kk < 16; ++kk) {
      const float4 av0 = *(const float4*)&As[kk][ty * 4];
      const float4 av1 = *(const float4*)&As[kk][64 + ty * 4];
      const float4 bv4 = *(const float4*)&Bs[kk][tx * 4];
      const float am[8] = {av0.x, av0.y, av0.z, av0.w, av1.x, av1.y, av1.z, av1.w};
      const float bn[4] = {bv4.x, bv4.y, bv4.z, bv4.w};
#pragma unroll
      for (int i2 = 0; i2 < 2; ++i2)
#pragma unroll
        for (int i = 0; i < 4; ++i)
#pragma unroll
          for (int j = 0; j < 4; ++j)
            acc[i2][i][j] += am[i2 * 4 + i] * bn[j];
    }
  }
#pragma unroll
  for (int i2 = 0; i2 < 2; ++i2)
#pragma unroll
    for (int i = 0; i < 4; ++i) {
      const int m = i2 * 64 + ty * 4 + i;
      *(float4*)(P + (size_t)m * N_NODES + n0 + tx * 4) =
          make_float4(acc[i2][i][0], acc[i2][i][1], acc[i2][i][2], acc[i2][i][3]);
    }
}

__global__ __launch_bounds__(256) void bias_inplace_kernel(float* __restrict__ P,
                                                           const float* __restrict__ bias) {
  const size_t base = ((size_t)blockIdx.x * 256 + threadIdx.x) * 4;
  const int n = (int)(base & (N_NODES - 1));
  float4 s = *(const float4*)(P + base);
  const float4 bv = *(const float4*)(bias + n);
  s.x += bv.x; s.y += bv.y; s.z += bv.z; s.w += bv.w;
  *(float4*)(P + base) = s;
}

// ---------------------------------------------------------------------------
// One workgroup per sample; state in registers (1024 thr x float4).
// MODE 1: prologue reduces NSPLIT GEMM partials + bias; ordered active-list
//         gather over encoded connT rows, 8-way unrolled.
// MODE 0: proj precomputed; f32 conn column gather (fallback).
// ---------------------------------------------------------------------------
template <int MODE, int NSPLIT>
__global__ __launch_bounds__(1024) void avalanche_kernel(const float* __restrict__ Pin,
                                                         const float* __restrict__ bias,
                                                         const void* __restrict__ connv,
                                                         float* __restrict__ out,
                                                         unsigned int* __restrict__ maxslot) {
  const int b = blockIdx.x;
  const int t = threadIdx.x;
  __shared__ unsigned long long mask[64];
  __shared__ int wincl[64];
  __shared__ int list[N_NODES];

  float4 s;
  if (MODE == 1) {
    const float4 bv = *(const float4*)(bias + t * 4);
    s = bv;
#pragma unroll
    for (int sp = 0; sp < NSPLIT; ++sp) {
      const float4 v = *(const float4*)(Pin + (size_t)sp * BATCH * N_NODES +
                                        (size_t)b * N_NODES + t * 4);
      s.x += v.x; s.y += v.y; s.z += v.z; s.w += v.w;
    }
  } else {
    s = *(const float4*)(Pin + (size_t)b * N_NODES + t * 4);
  }

  float total = 0.0f;

  for (int it = 0; it < 100; ++it) {
    const float v0 = s.x, v1 = s.y, v2 = s.z, v3 = s.w;
    unsigned int bits = 0;
    if (v0 > 1.0f) bits |= 1u;
    if (v1 > 1.0f) bits |= 2u;
    if (v2 > 1.0f) bits |= 4u;
    if (v3 > 1.0f) bits |= 8u;

    __syncthreads();
    if (t < 64) mask[t] = 0ULL;
    __syncthreads();
    if (bits) atomicOr(&mask[t >> 4], (unsigned long long)bits << ((t & 15) * 4));
    __syncthreads();

    if (t < 64) {
      int incl = __popcll(mask[t]);
#pragma unroll
      for (int d = 1; d < 64; d <<= 1) {
        const int y = __shfl_up(incl, d);
        if (t >= d) incl += y;
      }
      wincl[t] = incl;
    }
    __syncthreads();
    const int n = wincl[63];
    if (n == 0) break;  // sticky done: state frozen
    total += (float)n;

    if (t < 64) {
      unsigned long long m = mask[t];
      int o = wincl[t] - __popcll(m);
      while (m) {
        list[o++] = (t << 6) + __builtin_ctzll(m);
        m &= m - 1;
      }
    }
    __syncthreads();

    float4 a0 = make_float4(0.f, 0.f, 0.f, 0.f), a1 = a0, a2 = a0, a3 = a0;
    if (MODE == 1) {
      int idx = 0;
      for (; idx + 8 <= n; idx += 8) {
        const float4 c0 = conn_load4(connv, list[idx + 0], t);
        const float4 c1 = conn_load4(connv, list[idx + 1], t);
        const float4 c2 = conn_load4(connv, list[idx + 2], t);
        const float4 c3 = conn_load4(connv, list[idx + 3], t);
        const float4 c4 = conn_load4(connv, list[idx + 4], t);
        const float4 c5 = conn_load4(connv, list[idx + 5], t);
        const float4 c6 = conn_load4(connv, list[idx + 6], t);
        const float4 c7 = conn_load4(connv, list[idx + 7], t);
        a0.x += c0.x; a0.y += c0.y; a0.z += c0.z; a0.w += c0.w;
        a1.x += c1.x; a1.y += c1.y; a1.z += c1.z; a1.w += c1.w;
        a2.x += c2.x; a2.y += c2.y; a2.z += c2.z; a2.w += c2.w;
        a3.x += c3.x; a3.y += c3.y; a3.z += c3.z; a3.w += c3.w;
        a0.x += c4.x; a0.y += c4.y; a0.z += c4.z; a0.w += c4.w;
        a1.x += c5.x; a1.y += c5.y; a1.z += c5.z; a1.w += c5.w;
        a2.x += c6.x; a2.y += c6.y; a2.z += c6.z; a2.w += c6.w;
        a3.x += c7.x; a3.y += c7.y; a3.z += c7.z; a3.w += c7.w;
      }
      for (; idx < n; ++idx) {
        const float4 c = conn_load4(connv, list[idx], t);
        a0.x += c.x; a0.y += c.y; a0.z += c.z; a0.w += c.w;
      }
    } else {
      const float* conn = (const float*)connv;
      for (int idx = 0; idx < n; ++idx) {
        const int j = list[idx];
        a0.x += conn[(size_t)(t * 4 + 0) * N_NODES + j];
        a0.y += conn[(size_t)(t * 4 + 1) * N_NODES + j];
        a0.z += conn[(size_t)(t * 4 + 2) * N_NODES + j];
        a0.w += conn[(size_t)(t * 4 + 3) * N_NODES + j];
      }
    }
    const float sc = (MODE == 1) ? CONN_SCALE : 1.0f;
    const float4 acc = make_float4(((a0.x + a1.x) + (a2.x + a3.x)) * sc,
                                   ((a0.y + a1.y) + (a2.y + a3.y)) * sc,
                                   ((a0.z + a1.z) + (a2.z + a3.z)) * sc,
                                   ((a0.w + a1.w) + (a2.w + a3.w)) * sc);

    s.x = (v0 > 1.0f) ? 0.0f : 0.9f * v0 + acc.x;
    s.y = (v1 > 1.0f) ? 0.0f : 0.9f * v1 + acc.y;
    s.z = (v2 > 1.0f) ? 0.0f : 0.9f * v2 + acc.z;
    s.w = (v3 > 1.0f) ? 0.0f : 0.9f * v3 + acc.w;
  }

  *(float4*)(out + (size_t)b * N_NODES + t * 4) = s;
  if (t == 0) atomicMax(maxslot, __float_as_uint(total));  // totals >= 0
}

// ---------------------------------------------------------------------------
extern "C" void kernel_launch(void* const* d_in, const int* in_sizes, int n_in,
                              void* d_out, int out_size, void* d_ws, size_t ws_size,
                              hipStream_t stream) {
  const float* input = (const float*)d_in[0];  // [128,4096]
  const float* W     = (const float*)d_in[1];  // [4096,4096]
  const float* bias  = (const float*)d_in[2];  // [4096]
  const float* conn  = (const float*)d_in[3];  // [4096,4096]
  float* out = (float*)d_out;                  // [128*4096] state + [1] max_size

  const size_t connT_bytes = (size_t)N_NODES * N_NODES * CONN_ELEM_BYTES;
  const size_t part_bytes  = (size_t)SPLITK * BATCH * N_NODES * sizeof(float);  // 16 MB
  unsigned int* maxslot = (unsigned int*)(out + (size_t)BATCH * N_NODES);

  if (ws_size >= connT_bytes + part_bytes) {
    void* connT = d_ws;
    float* part = (float*)((char*)d_ws + connT_bytes);
    fused_prep_kernel<<<GEMM_BLOCKS + TRANS_BLOCKS, 256, 0, stream>>>(input, W, conn, part,
                                                                      connT, maxslot);
    avalanche_kernel<1, SPLITK><<<BATCH, 1024, 0, stream>>>(part, bias, connT, out, maxslot);
  } else {
    // Fallback: no workspace — f32 GEMM into d_out, in-place bias, strided gather.
    proj_gemm_valu<<<dim3(N_NODES / 64, 1), 256, 0, stream>>>(input, W, out, maxslot);
    bias_inplace_kernel<<<BATCH * N_NODES / 1024, 256, 0, stream>>>(out, bias);
    avalanche_kernel<0, 1><<<BATCH, 1024, 0, stream>>>(out, nullptr, conn, out, maxslot);
  }
}